// Round 8
// baseline (7335.850 us; speedup 1.0000x reference)
//
#include <hip/hip_runtime.h>

#define DIV_UP(a,b) (((a)+(b)-1)/(b))

// ---------------------------------------------------------------------------
// conv1 + pool1 fused: x[256,3,32,32] -> out[chunk,64,16,16]   (all f32)
// 3x3 pad1 + bias + relu + 2x2 maxpool. One block per (oc, n_local).
// ---------------------------------------------------------------------------
__global__ __launch_bounds__(256) void conv1_pool(
    const float* __restrict__ in, const float* __restrict__ w,
    const float* __restrict__ bias, float* __restrict__ out, int n0)
{
    __shared__ float in_s[3 * 34 * 34];   // 3468 floats
    __shared__ float w_s[27];
    __shared__ float c_s[32 * 32];
    const int tid = threadIdx.x;
    const int oc  = blockIdx.x;
    const int nl  = blockIdx.y;
    const int n   = n0 + nl;

    if (tid < 27) w_s[tid] = w[oc * 27 + tid];
    for (int idx = tid; idx < 3 * 34 * 34; idx += 256) {
        int c = idx / 1156;
        int r = idx - c * 1156;
        int y = r / 34;
        int x = r - y * 34;
        int iy = y - 1, ix = x - 1;
        float v = 0.f;
        if (iy >= 0 && iy < 32 && ix >= 0 && ix < 32)
            v = in[((n * 3 + c) * 32 + iy) * 32 + ix];
        in_s[idx] = v;
    }
    __syncthreads();
    const float bv = bias[oc];
#pragma unroll
    for (int p = 0; p < 4; ++p) {
        int px = tid + p * 256;
        int oy = px >> 5, ox = px & 31;
        float acc = bv;
#pragma unroll
        for (int c = 0; c < 3; ++c)
#pragma unroll
            for (int ky = 0; ky < 3; ++ky)
#pragma unroll
                for (int kx = 0; kx < 3; ++kx)
                    acc += in_s[c * 1156 + (oy + ky) * 34 + (ox + kx)]
                         * w_s[c * 9 + ky * 3 + kx];
        c_s[px] = fmaxf(acc, 0.f);
    }
    __syncthreads();
    {
        int oy = tid >> 4, ox = tid & 15;
        const float* p = &c_s[(2 * oy) * 32 + 2 * ox];
        float v = fmaxf(fmaxf(p[0], p[1]), fmaxf(p[32], p[33]));
        out[((nl * 64 + oc) * 16 + oy) * 16 + ox] = v;
    }
}

// ---------------------------------------------------------------------------
// conv2 + pool2 fused: in[chunk,64,16,16] -> out[chunk,192,8,8]
// 5x5 pad2 + bias + relu + 2x2 maxpool. Block = 64 threads, 4 ocs.
// ---------------------------------------------------------------------------
__global__ __launch_bounds__(64) void conv2_pool(
    const float* __restrict__ in, const float* __restrict__ w,
    const float* __restrict__ bias, float* __restrict__ out)
{
    __shared__ float in_s[20 * 20];
    __shared__ float w_s[4][25];
    const int tid = threadIdx.x;
    const int oc0 = blockIdx.x * 4;
    const int nl  = blockIdx.y;
    const int oy0 = (tid >> 3) * 2;
    const int ox0 = (tid & 7) * 2;

    float acc[4][2][2] = {};

    for (int ci = 0; ci < 64; ++ci) {
        __syncthreads();
        for (int idx = tid; idx < 400; idx += 64) {
            int y = idx / 20, x = idx - y * 20;
            int iy = y - 2, ix = x - 2;
            float v = 0.f;
            if (iy >= 0 && iy < 16 && ix >= 0 && ix < 16)
                v = in[((nl * 64 + ci) * 16 + iy) * 16 + ix];
            in_s[idx] = v;
        }
        {
            int g = tid / 25, k = tid - g * 25;   // tid 0..63 -> g 0..2
            w_s[g][k] = w[((oc0 + g) * 64 + ci) * 25 + k];
        }
        if (tid < 36) {
            int widx = tid + 64;
            int g = widx / 25, k = widx - g * 25;
            w_s[g][k] = w[((oc0 + g) * 64 + ci) * 25 + k];
        }
        __syncthreads();

        float r[6][6];
#pragma unroll
        for (int ry = 0; ry < 6; ++ry)
#pragma unroll
            for (int rx = 0; rx < 6; ++rx)
                r[ry][rx] = in_s[(oy0 + ry) * 20 + (ox0 + rx)];

#pragma unroll
        for (int g = 0; g < 4; ++g)
#pragma unroll
            for (int ky = 0; ky < 5; ++ky)
#pragma unroll
                for (int kx = 0; kx < 5; ++kx) {
                    float wv = w_s[g][ky * 5 + kx];
                    acc[g][0][0] += r[ky][kx] * wv;
                    acc[g][0][1] += r[ky][kx + 1] * wv;
                    acc[g][1][0] += r[ky + 1][kx] * wv;
                    acc[g][1][1] += r[ky + 1][kx + 1] * wv;
                }
    }

#pragma unroll
    for (int g = 0; g < 4; ++g) {
        float m = fmaxf(fmaxf(acc[g][0][0], acc[g][0][1]),
                        fmaxf(acc[g][1][0], acc[g][1][1]));
        float v = fmaxf(m + bias[oc0 + g], 0.f);
        out[((nl * 192 + oc0 + g) * 8 + (oy0 >> 1)) * 8 + (ox0 >> 1)] = v;
    }
}

// ---------------------------------------------------------------------------
// conv3/conv4 (3x3 pad1 + bias + relu), 8x8 planes. All f32.
// ---------------------------------------------------------------------------
template<int CIN>
__global__ __launch_bounds__(64) void conv3x3_relu(
    const float* __restrict__ in, const float* __restrict__ w,
    const float* __restrict__ bias, float* __restrict__ out, int Cout)
{
    __shared__ float in_s[10 * 10];
    __shared__ float w_s[36];
    const int tid = threadIdx.x;
    const int oc0 = blockIdx.x * 4;
    const int nl  = blockIdx.y;
    const int g   = tid >> 4;
    const int q   = tid & 15;
    const int oy0 = (q >> 2) * 2;
    const int ox0 = (q & 3) * 2;

    float acc[2][2] = {};

    for (int ci = 0; ci < CIN; ++ci) {
        __syncthreads();
        {
            int idx = tid;  // 0..63
            int y = idx / 10, x = idx - 10 * y;
            int iy = y - 1, ix = x - 1;
            in_s[idx] = (iy >= 0 && iy < 8 && ix >= 0 && ix < 8)
                          ? in[((nl * CIN + ci) * 8 + iy) * 8 + ix] : 0.f;
        }
        if (tid < 36) {
            int idx = tid + 64;  // 64..99
            int y = idx / 10, x = idx - 10 * y;
            int iy = y - 1, ix = x - 1;
            in_s[idx] = (iy >= 0 && iy < 8 && ix >= 0 && ix < 8)
                          ? in[((nl * CIN + ci) * 8 + iy) * 8 + ix] : 0.f;
        }
        if (tid >= 28) {  // 36 threads load 36 weights
            int widx = tid - 28;
            int gg = widx / 9, k = widx - 9 * gg;
            w_s[widx] = w[((oc0 + gg) * CIN + ci) * 9 + k];
        }
        __syncthreads();

        float r[4][4];
#pragma unroll
        for (int ry = 0; ry < 4; ++ry)
#pragma unroll
            for (int rx = 0; rx < 4; ++rx)
                r[ry][rx] = in_s[(oy0 + ry) * 10 + (ox0 + rx)];

#pragma unroll
        for (int ky = 0; ky < 3; ++ky)
#pragma unroll
            for (int kx = 0; kx < 3; ++kx) {
                float wv = w_s[g * 9 + ky * 3 + kx];
                acc[0][0] += r[ky][kx] * wv;
                acc[0][1] += r[ky][kx + 1] * wv;
                acc[1][0] += r[ky + 1][kx] * wv;
                acc[1][1] += r[ky + 1][kx + 1] * wv;
            }
    }

    const float bv = bias[oc0 + g];
#pragma unroll
    for (int i = 0; i < 2; ++i)
#pragma unroll
        for (int j = 0; j < 2; ++j)
            out[((nl * Cout + oc0 + g) * 8 + oy0 + i) * 8 + (ox0 + j)]
                = fmaxf(acc[i][j] + bv, 0.f);
}

// ---------------------------------------------------------------------------
// conv5 + pool5 fused: in[chunk,256,8,8] -> out[chunk,4096] (local rows, f32)
// ---------------------------------------------------------------------------
__global__ __launch_bounds__(64) void conv5_pool(
    const float* __restrict__ in, const float* __restrict__ w,
    const float* __restrict__ bias, float* __restrict__ out)
{
    __shared__ float in_s[10 * 10];
    __shared__ float w_s[36];
    const int tid = threadIdx.x;
    const int oc0 = blockIdx.x * 4;
    const int nl  = blockIdx.y;
    const int g   = tid >> 4;
    const int q   = tid & 15;
    const int oy0 = (q >> 2) * 2;
    const int ox0 = (q & 3) * 2;

    float acc[2][2] = {};

    for (int ci = 0; ci < 256; ++ci) {
        __syncthreads();
        {
            int idx = tid;
            int y = idx / 10, x = idx - 10 * y;
            int iy = y - 1, ix = x - 1;
            in_s[idx] = (iy >= 0 && iy < 8 && ix >= 0 && ix < 8)
                          ? in[((nl * 256 + ci) * 8 + iy) * 8 + ix] : 0.f;
        }
        if (tid < 36) {
            int idx = tid + 64;
            int y = idx / 10, x = idx - 10 * y;
            int iy = y - 1, ix = x - 1;
            in_s[idx] = (iy >= 0 && iy < 8 && ix >= 0 && ix < 8)
                          ? in[((nl * 256 + ci) * 8 + iy) * 8 + ix] : 0.f;
        }
        if (tid >= 28) {
            int widx = tid - 28;
            int gg = widx / 9, k = widx - 9 * gg;
            w_s[widx] = w[((oc0 + gg) * 256 + ci) * 9 + k];
        }
        __syncthreads();

        float r[4][4];
#pragma unroll
        for (int ry = 0; ry < 4; ++ry)
#pragma unroll
            for (int rx = 0; rx < 4; ++rx)
                r[ry][rx] = in_s[(oy0 + ry) * 10 + (ox0 + rx)];

#pragma unroll
        for (int ky = 0; ky < 3; ++ky)
#pragma unroll
            for (int kx = 0; kx < 3; ++kx) {
                float wv = w_s[g * 9 + ky * 3 + kx];
                acc[0][0] += r[ky][kx] * wv;
                acc[0][1] += r[ky][kx + 1] * wv;
                acc[1][0] += r[ky + 1][kx] * wv;
                acc[1][1] += r[ky + 1][kx + 1] * wv;
            }
    }

    float m = fmaxf(fmaxf(acc[0][0], acc[0][1]), fmaxf(acc[1][0], acc[1][1]));
    float v = fmaxf(m + bias[oc0 + g], 0.f);
    out[(long)nl * 4096 + (oc0 + g) * 16 + (oy0 >> 1) * 4 + (ox0 >> 1)] = v;
}

// ---------------------------------------------------------------------------
// FC: Y[M,N] = X[M,K] @ W[N,K]^T + bias (+relu). All f32. M <= 64 per y-block
// (M-guarded). Tiled 64x64x16, 256 thr, 4x4 microtile, float4 LDS reads.
// ---------------------------------------------------------------------------
template<bool RELU>
__global__ __launch_bounds__(256) void fc_gemm(
    const float* __restrict__ X, const float* __restrict__ W,
    const float* __restrict__ Bs, float* __restrict__ Y,
    int M, int N, int K)
{
    __shared__ __align__(16) float xs[16][68];
    __shared__ __align__(16) float ws_t[16][68];
    const int tid = threadIdx.x;
    const int m0 = blockIdx.y * 64;
    const int n0 = blockIdx.x * 64;
    const int lr = tid >> 2;          // 0..63
    const int lk = (tid & 3) << 2;    // 0,4,8,12
    const int tr = tid >> 4;          // 0..15
    const int tc = tid & 15;          // 0..15

    float acc[4][4] = {};

    for (int k0 = 0; k0 < K; k0 += 16) {
        float4 xv = make_float4(0.f, 0.f, 0.f, 0.f);
        if (m0 + lr < M)
            xv = *(const float4*)(X + (long)(m0 + lr) * K + k0 + lk);
        float4 wv = make_float4(0.f, 0.f, 0.f, 0.f);
        int nrow = n0 + lr;
        if (nrow < N)
            wv = *(const float4*)(W + (long)nrow * K + k0 + lk);
        __syncthreads();
        xs[lk + 0][lr] = xv.x; xs[lk + 1][lr] = xv.y;
        xs[lk + 2][lr] = xv.z; xs[lk + 3][lr] = xv.w;
        ws_t[lk + 0][lr] = wv.x; ws_t[lk + 1][lr] = wv.y;
        ws_t[lk + 2][lr] = wv.z; ws_t[lk + 3][lr] = wv.w;
        __syncthreads();
#pragma unroll
        for (int k = 0; k < 16; ++k) {
            float4 av = *(const float4*)(&xs[k][tr << 2]);
            float4 bv = *(const float4*)(&ws_t[k][tc << 2]);
            float a[4] = {av.x, av.y, av.z, av.w};
            float b[4] = {bv.x, bv.y, bv.z, bv.w};
#pragma unroll
            for (int i = 0; i < 4; ++i)
#pragma unroll
                for (int j = 0; j < 4; ++j)
                    acc[i][j] += a[i] * b[j];
        }
    }

#pragma unroll
    for (int i = 0; i < 4; ++i) {
        int m = m0 + tr * 4 + i;
        if (m < M) {
#pragma unroll
            for (int j = 0; j < 4; ++j) {
                int nn = n0 + tc * 4 + j;
                if (nn < N) {
                    float v = acc[i][j] + Bs[nn];
                    if (RELU) v = fmaxf(v, 0.f);
                    Y[(long)m * N + nn] = v;
                }
            }
        }
    }
}

// Fallback if ws_size is too small to run anything: finite zeros.
__global__ void zero_out(float* __restrict__ out, int total)
{
    int i = blockIdx.x * 256 + threadIdx.x;
    if (i < total) out[i] = 0.f;
}

// ---------------------------------------------------------------------------
extern "C" void kernel_launch(void* const* d_in, const int* in_sizes, int n_in,
                              void* d_out, int out_size, void* d_ws, size_t ws_size,
                              hipStream_t stream)
{
    (void)in_sizes; (void)n_in;
    const float* x   = (const float*)d_in[0];
    const float* w1  = (const float*)d_in[1];
    const float* b1  = (const float*)d_in[2];
    const float* w2  = (const float*)d_in[3];
    const float* b2  = (const float*)d_in[4];
    const float* w3  = (const float*)d_in[5];
    const float* b3  = (const float*)d_in[6];
    const float* w4  = (const float*)d_in[7];
    const float* b4  = (const float*)d_in[8];
    const float* w5  = (const float*)d_in[9];
    const float* b5  = (const float*)d_in[10];
    const float* fw1 = (const float*)d_in[11];
    const float* fb1 = (const float*)d_in[12];
    const float* fw2 = (const float*)d_in[13];
    const float* fb2 = (const float*)d_in[14];
    const float* fw3 = (const float*)d_in[15];
    const float* fb3 = (const float*)d_in[16];
    float* out = (float*)d_out;

    // Per-chunk ws layout (f32 elements), chunk = CH samples; whole network
    // conv1..fc3 per chunk, fc3 rows straight into d_out.
    //   CA : CH*24576  (conv1 out / conv3 out / fc1 out)
    //   CB : CH*16384  (conv2 out / conv4 out / fc2 out)
    //   TC : CH*4096   (conv5+pool out = fc1 input)
    // bytes = CH * 45056 * 4 = CH * 180224.  CH=64 -> 11.53MB, CH=1 -> 176KB.
    const size_t NEED1 = 180224u;
    if (ws_size < NEED1) {
        zero_out<<<DIV_UP(out_size, 256), 256, 0, stream>>>(out, out_size);
        return;
    }

    int CH = 64;
    while (CH > 1 && (size_t)CH * NEED1 > ws_size) CH >>= 1;

    float* CA = (float*)d_ws;
    float* CB = CA + (size_t)CH * 24576;
    float* TC = CB + (size_t)CH * 16384;

    for (int n0 = 0; n0 < 256; n0 += CH) {
        conv1_pool<<<dim3(64, CH), 256, 0, stream>>>(x, w1, b1, CA, n0);
        conv2_pool<<<dim3(192 / 4, CH), 64, 0, stream>>>(CA, w2, b2, CB);
        conv3x3_relu<192><<<dim3(384 / 4, CH), 64, 0, stream>>>(CB, w3, b3, CA, 384);
        conv3x3_relu<384><<<dim3(256 / 4, CH), 64, 0, stream>>>(CA, w4, b4, CB, 256);
        conv5_pool<<<dim3(256 / 4, CH), 64, 0, stream>>>(CB, w5, b5, TC);
        // fc1 + relu: TC[CH,4096] -> CA[CH,4096]   (M=CH, N=4096, K=4096)
        fc_gemm<true><<<dim3(4096 / 64, DIV_UP(CH, 64)), 256, 0, stream>>>(
            TC, fw1, fb1, CA, CH, 4096, 4096);
        // fc2 + relu: CA -> CB[CH,4096]            (M=CH, N=4096, K=4096)
        fc_gemm<true><<<dim3(4096 / 64, DIV_UP(CH, 64)), 256, 0, stream>>>(
            CA, fw2, fb2, CB, CH, 4096, 4096);
        // fc3: CB -> out rows [n0, n0+CH)          (M=CH, N=1000, K=4096)
        // BUG FIX (r0..r7): N/K were swapped (4096,1000) at this call site.
        fc_gemm<false><<<dim3(DIV_UP(1000, 64), DIV_UP(CH, 64)), 256, 0, stream>>>(
            CB, fw3, fb3, out + (long)n0 * 1000, CH, 1000, 4096);
    }
}

// Round 9
// 1045.278 us; speedup vs baseline: 7.0181x; 7.0181x over previous
//
#include <hip/hip_runtime.h>
#include <hip/hip_bf16.h>

#define DIV_UP(a,b) (((a)+(b)-1)/(b))

typedef __attribute__((ext_vector_type(8))) short bfrag;   // 8 bf16 = 4 VGPR
typedef __attribute__((ext_vector_type(4))) float accf;    // MFMA acc

__device__ __forceinline__ unsigned short f2bf(float f) {
    __hip_bfloat16 h = __float2bfloat16(f);
    return *reinterpret_cast<unsigned short*>(&h);
}

// ---------------------------------------------------------------------------
// conv1 + pool1 (VALU, small): x[256,3,32,32] f32 -> CA[chunk,64,16,16] bf16
// ---------------------------------------------------------------------------
__global__ __launch_bounds__(256) void conv1_pool(
    const float* __restrict__ in, const float* __restrict__ w,
    const float* __restrict__ bias, unsigned short* __restrict__ out, int n0)
{
    __shared__ float in_s[3 * 34 * 34];
    __shared__ float w_s[27];
    __shared__ float c_s[32 * 32];
    const int tid = threadIdx.x;
    const int oc  = blockIdx.x;
    const int nl  = blockIdx.y;
    const int n   = n0 + nl;

    if (tid < 27) w_s[tid] = w[oc * 27 + tid];
    for (int idx = tid; idx < 3 * 34 * 34; idx += 256) {
        int c = idx / 1156;
        int r = idx - c * 1156;
        int y = r / 34;
        int x = r - y * 34;
        int iy = y - 1, ix = x - 1;
        float v = 0.f;
        if (iy >= 0 && iy < 32 && ix >= 0 && ix < 32)
            v = in[((n * 3 + c) * 32 + iy) * 32 + ix];
        in_s[idx] = v;
    }
    __syncthreads();
    const float bv = bias[oc];
#pragma unroll
    for (int p = 0; p < 4; ++p) {
        int px = tid + p * 256;
        int oy = px >> 5, ox = px & 31;
        float acc = bv;
#pragma unroll
        for (int c = 0; c < 3; ++c)
#pragma unroll
            for (int ky = 0; ky < 3; ++ky)
#pragma unroll
                for (int kx = 0; kx < 3; ++kx)
                    acc += in_s[c * 1156 + (oy + ky) * 34 + (ox + kx)]
                         * w_s[c * 9 + ky * 3 + kx];
        c_s[px] = fmaxf(acc, 0.f);
    }
    __syncthreads();
    {
        int oy = tid >> 4, ox = tid & 15;
        const float* p = &c_s[(2 * oy) * 32 + 2 * ox];
        float v = fmaxf(fmaxf(p[0], p[1]), fmaxf(p[32], p[33]));
        out[((nl * 64 + oc) * 16 + oy) * 16 + ox] = f2bf(v);
    }
}

// ---------------------------------------------------------------------------
// MFMA implicit-GEMM conv. bf16 in [nl][CIN][HIN*HIN], f32 weights OIHW,
// f32 bias. Block = 256 thr (4 waves), N = 64 ocs (wave w: oc0+w*16+lr),
// M = MROWS*HIN pixels (row band rb). K-loop: ci chunks of 32 x kidx groups.
// A-frag: one ds_read_b128 from in_s[pos][ci] (OOB -> zero slot at pos=PIX).
// MODE: 0 = relu->out[nl][COUT][PIX]; 1 = 2x2 pool -> [nl][COUT][PIX/4];
//       2 = 2x2 pool -> T5[nl*4096 + oc*16 + opix].
// ---------------------------------------------------------------------------
template<int CIN, int KS, int HIN, int MROWS, int MODE, int KG, int COUT>
__global__ __launch_bounds__(256) void conv_mfma(
    const unsigned short* __restrict__ in, const float* __restrict__ w,
    const float* __restrict__ bias, unsigned short* __restrict__ out)
{
    constexpr int PAD  = KS / 2;
    constexpr int KK   = KS * KS;
    constexpr int PIX  = HIN * HIN;
    constexpr int M    = MROWS * HIN;
    constexpr int MT   = M / 16;
    constexpr int ROWB = HIN / MROWS;
    constexpr int INS  = PIX * 32 + 32;            // shorts (incl zero slot)
    constexpr int WSZ  = KG * 64 * 32;             // shorts
    constexpr int CS   = M * 66;                   // floats
    constexpr int SMEM = ((INS + WSZ) * 2 > CS * 4) ? (INS + WSZ) * 2 : CS * 4;

    __shared__ __align__(16) char smem[SMEM];
    short* in_s = (short*)smem;
    short* w_s  = in_s + INS;
    float* c_s  = (float*)smem;

    const int tid  = threadIdx.x;
    const int lane = tid & 63, wv = tid >> 6;
    const int quad = lane >> 4, lr = lane & 15;
    const int ocb  = blockIdx.x / ROWB, rb = blockIdx.x % ROWB;
    const int oc0  = ocb * 64;
    const int nl   = blockIdx.y;
    const int row0 = rb * MROWS;

    if (tid < 32) in_s[PIX * 32 + tid] = 0;        // zero slot for OOB taps

    accf acc[MT];
#pragma unroll
    for (int i = 0; i < MT; ++i) acc[i] = (accf){0.f, 0.f, 0.f, 0.f};

    const int sci = tid & 31, slot = tid >> 5;

    for (int c0 = 0; c0 < CIN; c0 += 32) {
#pragma unroll
        for (int kg = 0; kg < KK; kg += KG) {
            __syncthreads();
            if (kg == 0) {
                // stage input channel c0+sci, all rows -> in_s[pos][ci]
                const unsigned short* src = in + ((size_t)(nl * CIN + c0 + sci)) * PIX;
                for (int iy = slot; iy < HIN; iy += 8) {
#pragma unroll
                    for (int xc = 0; xc < HIN; xc += 8) {
                        uint4 v = *(const uint4*)(src + iy * HIN + xc);
                        int base = (iy * HIN + xc) * 32 + sci;
                        in_s[base + 0 * 32] = (short)(v.x & 0xFFFF);
                        in_s[base + 1 * 32] = (short)(v.x >> 16);
                        in_s[base + 2 * 32] = (short)(v.y & 0xFFFF);
                        in_s[base + 3 * 32] = (short)(v.y >> 16);
                        in_s[base + 4 * 32] = (short)(v.z & 0xFFFF);
                        in_s[base + 5 * 32] = (short)(v.z >> 16);
                        in_s[base + 6 * 32] = (short)(v.w & 0xFFFF);
                        in_s[base + 7 * 32] = (short)(v.w >> 16);
                    }
                }
            }
            {   // stage weights for kidx in [kg, kg+KG): w_s[g][oc][ci]
                const int oc = tid >> 2, cb = (tid & 3) * 8;
#pragma unroll
                for (int j = 0; j < 8; ++j) {
                    const float* wp = w + ((size_t)(oc0 + oc) * CIN + (c0 + cb + j)) * KK + kg;
#pragma unroll
                    for (int g = 0; g < KG; ++g)
                        w_s[(g * 64 + oc) * 32 + cb + j] = (short)f2bf(wp[g]);
                }
            }
            __syncthreads();
#pragma unroll
            for (int g = 0; g < KG; ++g) {
                const int kidx = kg + g;
                const int dy = kidx / KS - PAD, dx = kidx % KS - PAD;
                const bfrag b = *(const bfrag*)(w_s + (g * 64 + wv * 16 + lr) * 32 + quad * 8);
#pragma unroll
                for (int mt = 0; mt < MT; ++mt) {
                    const int m  = mt * 16 + lr;
                    const int py = row0 + m / HIN, px = m % HIN;
                    const int iy = py + dy, ix = px + dx;
                    const bool ok = ((unsigned)iy < (unsigned)HIN) &
                                    ((unsigned)ix < (unsigned)HIN);
                    const int pos = ok ? (iy * HIN + ix) : PIX;
                    const bfrag a = *(const bfrag*)(in_s + pos * 32 + quad * 8);
                    acc[mt] = __builtin_amdgcn_mfma_f32_16x16x32_bf16(a, b, acc[mt], 0, 0, 0);
                }
            }
        }
    }

    __syncthreads();
    // acc -> c_s[m][oc]  (row = D m = quad*4+reg, col = D n = lr)
#pragma unroll
    for (int mt = 0; mt < MT; ++mt)
#pragma unroll
        for (int r = 0; r < 4; ++r)
            c_s[(mt * 16 + quad * 4 + r) * 66 + wv * 16 + lr] = acc[mt][r];
    __syncthreads();

    const int oc = tid >> 2;
    const float bv = bias[oc0 + oc];
    if (MODE == 0) {
        const int p0 = (tid & 3) * (M / 4);        // M/4 = 16
        __align__(16) unsigned short buf[16];
#pragma unroll
        for (int i = 0; i < 16; ++i)
            buf[i] = f2bf(fmaxf(c_s[(p0 + i) * 66 + oc] + bv, 0.f));
        unsigned short* dst = out + ((size_t)(nl * COUT + oc0 + oc)) * PIX + row0 * HIN + p0;
        *(uint4*)(dst)     = *(uint4*)(buf);
        *(uint4*)(dst + 8) = *(uint4*)(buf + 8);
    } else if (MODE == 1) {
        constexpr int OW = HIN / 2;
        constexpr int OM = (MROWS / 2) * OW;       // 32 outputs per oc per block
        const int o0 = (tid & 3) * (OM / 4);       // 8 each
        __align__(16) unsigned short buf[OM / 4];
#pragma unroll
        for (int i = 0; i < OM / 4; ++i) {
            int op = o0 + i, oy = op / OW, ox = op % OW;
            int p = (oy * 2) * HIN + ox * 2;
            float v = fmaxf(fmaxf(c_s[p * 66 + oc],        c_s[(p + 1) * 66 + oc]),
                            fmaxf(c_s[(p + HIN) * 66 + oc], c_s[(p + HIN + 1) * 66 + oc]));
            buf[i] = f2bf(fmaxf(v + bv, 0.f));
        }
        unsigned short* dst = out + ((size_t)(nl * COUT + oc0 + oc)) * (PIX / 4)
                            + (row0 / 2) * OW + o0;
        *(uint4*)dst = *(uint4*)buf;
    } else { // MODE 2: HIN=8 -> 4x4 pooled into T5 rows
        const int o0 = (tid & 3) * 4;
        __align__(16) unsigned short buf[4];
#pragma unroll
        for (int i = 0; i < 4; ++i) {
            int op = o0 + i, oy = op >> 2, ox = op & 3;
            int p = (oy * 2) * 8 + ox * 2;
            float v = fmaxf(fmaxf(c_s[p * 66 + oc],       c_s[(p + 1) * 66 + oc]),
                            fmaxf(c_s[(p + 8) * 66 + oc], c_s[(p + 9) * 66 + oc]));
            buf[i] = f2bf(fmaxf(v + bv, 0.f));
        }
        *(uint2*)(out + (size_t)nl * 4096 + (oc0 + oc) * 16 + o0) = *(uint2*)buf;
    }
}

// ---------------------------------------------------------------------------
// FC MFMA: Y[M=256,N] = X(bf16)[M,K] @ W(f32)[N,K]^T + bias (+relu).
// Grid (N/64, 4); block 256 thr; wave w: N16 slice; M64 per block.
// ---------------------------------------------------------------------------
template<bool RELU, bool F32OUT>
__global__ __launch_bounds__(256) void fc_mfma(
    const unsigned short* __restrict__ X, const float* __restrict__ W,
    const float* __restrict__ Bs, void* __restrict__ Yv, int N, int K)
{
    __shared__ __align__(16) short Xs[64 * 32];
    __shared__ __align__(16) short Ws[64 * 32];
    const int tid  = threadIdx.x;
    const int lane = tid & 63, wv = tid >> 6;
    const int quad = lane >> 4, lr = lane & 15;
    const int m0 = blockIdx.y * 64, n0 = blockIdx.x * 64;
    const int mm = tid >> 2, ko = (tid & 3) * 8;

    accf acc[4];
#pragma unroll
    for (int i = 0; i < 4; ++i) acc[i] = (accf){0.f, 0.f, 0.f, 0.f};

    int nr = n0 + mm; if (nr > N - 1) nr = N - 1;
    const unsigned short* xp = X + (size_t)(m0 + mm) * K + ko;
    const float*          wp = W + (size_t)nr * K + ko;

    for (int k0 = 0; k0 < K; k0 += 32) {
        uint4  xv = *(const uint4*)(xp + k0);
        float4 wa = *(const float4*)(wp + k0);
        float4 wb = *(const float4*)(wp + k0 + 4);
        __syncthreads();
        *(uint4*)&Xs[mm * 32 + ko] = xv;
        __align__(16) unsigned short wb16[8] = {
            f2bf(wa.x), f2bf(wa.y), f2bf(wa.z), f2bf(wa.w),
            f2bf(wb.x), f2bf(wb.y), f2bf(wb.z), f2bf(wb.w) };
        *(uint4*)&Ws[mm * 32 + ko] = *(uint4*)wb16;
        __syncthreads();
        const bfrag b = *(const bfrag*)(Ws + (wv * 16 + lr) * 32 + quad * 8);
#pragma unroll
        for (int mt = 0; mt < 4; ++mt) {
            const bfrag a = *(const bfrag*)(Xs + (mt * 16 + lr) * 32 + quad * 8);
            acc[mt] = __builtin_amdgcn_mfma_f32_16x16x32_bf16(a, b, acc[mt], 0, 0, 0);
        }
    }

    const int n = n0 + wv * 16 + lr;
    const float bv = (n < N) ? Bs[n] : 0.f;
#pragma unroll
    for (int mt = 0; mt < 4; ++mt)
#pragma unroll
        for (int r = 0; r < 4; ++r) {
            const int m = m0 + mt * 16 + quad * 4 + r;
            float v = acc[mt][r] + bv;
            if (RELU) v = fmaxf(v, 0.f);
            if (n < N) {
                if (F32OUT) ((float*)Yv)[(size_t)m * N + n] = v;
                else ((unsigned short*)Yv)[(size_t)m * N + n] = f2bf(v);
            }
        }
}

// Fallback if ws too small: finite zeros.
__global__ void zero_out(float* __restrict__ out, int total)
{
    int i = blockIdx.x * 256 + threadIdx.x;
    if (i < total) out[i] = 0.f;
}

// ---------------------------------------------------------------------------
extern "C" void kernel_launch(void* const* d_in, const int* in_sizes, int n_in,
                              void* d_out, int out_size, void* d_ws, size_t ws_size,
                              hipStream_t stream)
{
    (void)in_sizes; (void)n_in;
    const float* x   = (const float*)d_in[0];
    const float* w1  = (const float*)d_in[1];
    const float* b1  = (const float*)d_in[2];
    const float* w2  = (const float*)d_in[3];
    const float* b2  = (const float*)d_in[4];
    const float* w3  = (const float*)d_in[5];
    const float* b3  = (const float*)d_in[6];
    const float* w4  = (const float*)d_in[7];
    const float* b4  = (const float*)d_in[8];
    const float* w5  = (const float*)d_in[9];
    const float* b5  = (const float*)d_in[10];
    const float* fw1 = (const float*)d_in[11];
    const float* fb1 = (const float*)d_in[12];
    const float* fw2 = (const float*)d_in[13];
    const float* fb2 = (const float*)d_in[14];
    const float* fw3 = (const float*)d_in[15];
    const float* fb3 = (const float*)d_in[16];
    float* out = (float*)d_out;

    // ws layout (bytes), all bf16 activations:
    //   CA @ 0        : 3 MB  (conv1 out [64,64,256] 2MB / conv3 out [64,384,64] 3MB / fc1 out 2MB)
    //   CB @ 3 MB     : 2 MB  (conv2 out 1.5MB / conv4 out 2MB / fc2 out 2MB)
    //   T5 @ 5 MB     : 2 MB  ([256,4096] fc input)
    // total 7 MB; r8 proved ws_size >= 11.5 MB (CH=64 ran in-bounds).
    const size_t NEED = 7u * 1024u * 1024u;
    if (ws_size < NEED) {
        zero_out<<<DIV_UP(out_size, 256), 256, 0, stream>>>(out, out_size);
        return;
    }
    unsigned short* CA = (unsigned short*)d_ws;
    unsigned short* CB = (unsigned short*)((char*)d_ws + 3u * 1024u * 1024u);
    unsigned short* T5 = (unsigned short*)((char*)d_ws + 5u * 1024u * 1024u);

    const int CH = 64;
    for (int n0 = 0; n0 < 256; n0 += CH) {
        // conv1+pool: x -> CA [CH,64,16,16] bf16
        conv1_pool<<<dim3(64, CH), 256, 0, stream>>>(x, w1, b1, CA, n0);
        // conv2+pool (5x5, 16x16, 2 row-bands): CA -> CB [CH,192,8,8]
        conv_mfma<64, 5, 16, 8, 1, 5, 192><<<dim3(6, CH), 256, 0, stream>>>(CA, w2, b2, CB);
        // conv3: CB -> CA [CH,384,8,8]
        conv_mfma<192, 3, 8, 8, 0, 9, 384><<<dim3(6, CH), 256, 0, stream>>>(CB, w3, b3, CA);
        // conv4: CA -> CB [CH,256,8,8]
        conv_mfma<384, 3, 8, 8, 0, 9, 256><<<dim3(4, CH), 256, 0, stream>>>(CA, w4, b4, CB);
        // conv5+pool: CB -> T5 rows [n0, n0+CH)
        conv_mfma<256, 3, 8, 8, 2, 9, 256><<<dim3(4, CH), 256, 0, stream>>>(
            CB, w5, b5, T5 + (size_t)n0 * 4096);
    }

    // fc1 + relu: T5[256,4096] -> CA (bf16 [256,4096])
    fc_mfma<true, false><<<dim3(64, 4), 256, 0, stream>>>(T5, fw1, fb1, CA, 4096, 4096);
    // fc2 + relu: CA -> CB
    fc_mfma<true, false><<<dim3(64, 4), 256, 0, stream>>>(CA, fw2, fb2, CB, 4096, 4096);
    // fc3: CB -> out f32 [256,1000]
    fc_mfma<false, true><<<dim3(16, 4), 256, 0, stream>>>(CB, fw3, fb3, out, 1000, 4096);
}